// Round 7
// baseline (111.522 us; speedup 1.0000x reference)
//
#include <hip/hip_runtime.h>

#define HH 128
#define WW 128
#define NPIX (HH*WW)
#define NC 35
#define NB1 512            // prep/norm blocks (64 px each)
#define NWIN 8             // 2048-pixel windows per batch
#define WPX 2048
#define NGB (NC*NWIN)      // 280 gemm blocks per batch
#define NG (2*NGB)         // 560 total gemm blocks

// ---- K1: transpose x -> xt (pixel-major, +conv scalar), argmax -> argbuf; blk0 zeroes sums
__global__ __launch_bounds__(256) void prep_kernel(
    const float* __restrict__ x, const float* __restrict__ layout,
    const float* __restrict__ pr, const float* __restrict__ cw,
    const float* __restrict__ cb, const float* __restrict__ pl,
    float* __restrict__ xt, int* __restrict__ argbuf, float* __restrict__ sums)
{
    __shared__ float s_t[64*65];   // [c][p] stride 65
    __shared__ float s_s[64];

    const int t  = threadIdx.x;
    const int bk = blockIdx.x;           // 512: b(2) x ptile(256)
    const int b  = bk >> 8;
    const int p0 = (bk & 255) << 6;
    const int h  = p0 >> 7;
    const int w0 = p0 & 127;

    if (bk == 0) sums[t] = 0.f;          // 256 floats = 128 (b,o) x {S,SS}

    // stage x tile (64c x 64p) into LDS, coalesced float4
    const float4* x4 = (const float4*)x + (size_t)b*64*4096 + (p0 >> 2);
    #pragma unroll
    for (int k = 0; k < 4; ++k) {
        int f = k*256 + t;
        int c = f >> 4, i = f & 15;
        float4 q = x4[c*4096 + i];
        int base = c*65 + i*4;
        s_t[base+0]=q.x; s_t[base+1]=q.y; s_t[base+2]=q.z; s_t[base+3]=q.w;
    }

    if (t < 64) {
        // conv scalar s for pixel p0+t
        int w = w0 + t;
        float pxv = (float)h * (2.0f/128.0f) - 1.0f;
        float pyv = (float)w * (2.0f/128.0f) - 1.0f;
        float pl0 = pl[h*WW + w];
        float pl1 = pl[NPIX + h*WW + w];
        float pr0 = pr[((b*2+0)*HH + h)*WW + w];
        float pr1 = pr[((b*2+1)*HH + h)*WW + w];
        int kx = w % 3, kyy = h % 3;
        const float C1 = -0.5f, S1 = 0.86602540378443864676f;
        float xcv = (kx==0)  ? 1.0f : C1;
        float xsv = (kx==0)  ? 0.0f : ((kx==1)  ? S1 : -S1);
        float ycv = (kyy==0) ? 1.0f : C1;
        float ysv = (kyy==0) ? 0.0f : ((kyy==1) ? S1 : -S1);
        s_s[t] = cb[0] + pxv*cw[0] + pyv*cw[1] + pl0*cw[2] + pl1*cw[3]
               + pr0*cw[4] + pr1*cw[5] + xcv*cw[6] + xsv*cw[7]
               + ycv*cw[8] + ysv*cw[9];
    } else if (t < 128) {
        // argmax (first-max) for pixel p0+lane
        int lane = t - 64;
        const float* lp = layout + (size_t)(b*NC)*NPIX + p0 + lane;
        float best = lp[0]; int bj = 0;
        #pragma unroll
        for (int c = 1; c < NC; ++c) {
            float v = lp[(size_t)c*NPIX];
            if (v > best) { best = v; bj = c; }
        }
        argbuf[b*NPIX + p0 + lane] = bj;     // coalesced 256B
    }
    __syncthreads();

    // write xt[b][p][c] = x + s, coalesced 1KB/instr
    float4* xt4 = (float4*)xt + ((size_t)b*NPIX + p0)*16;
    #pragma unroll
    for (int k = 0; k < 4; ++k) {
        int g = k*256 + t;
        int p = g >> 4, c4 = g & 15;
        float sp = s_s[p];
        float4 q;
        q.x = s_t[(c4*4+0)*65 + p] + sp;
        q.y = s_t[(c4*4+1)*65 + p] + sp;
        q.z = s_t[(c4*4+2)*65 + p] + sp;
        q.w = s_t[(c4*4+3)*65 + p] + sp;
        xt4[p*16 + c4] = q;
    }
}

// ---- K2: self-selecting bucketed matvec. Block = (b, label, 2048-px window).
//      Ballot-compacts matches into LDS; W_l column in 64 VGPRs/lane (lane=o).
//      Per-(b,o) sum/sumsq via fire-and-forget atomics (cheap; no return value).
__global__ __launch_bounds__(256) void gemm_kernel(
    const float* __restrict__ Wt, const float* __restrict__ bt,
    const float* __restrict__ xt, const int* __restrict__ argbuf,
    float* __restrict__ yt, float* __restrict__ sums)
{
    const int g   = blockIdx.x;          // b-major
    const int b   = g / NGB;
    const int rem = g % NGB;
    const int l   = rem >> 3;
    const int win = rem & (NWIN-1);
    const int t = threadIdx.x, wv = t >> 6, lane = t & 63;

    __shared__ int   s_list[WPX];
    __shared__ int   s_n;
    __shared__ float s_x[64*64];         // [p][c]
    __shared__ float s_red[4][64][2];

    if (t == 0) s_n = 0;
    __syncthreads();

    // ---- ballot compaction of this window's matches (order-free) ----
    const int wpix = win*WPX;
    #pragma unroll
    for (int j = 0; j < WPX/256; ++j) {
        int idx = wv*(WPX/4) + j*64 + lane;
        int a = argbuf[b*NPIX + wpix + idx];
        bool match = (a == l);
        unsigned long long mask = __ballot(match);
        int total = __popcll(mask);
        if (total) {
            int base = 0;
            if (lane == 0) base = atomicAdd(&s_n, total);   // LDS atomic
            base = __shfl(base, 0);
            if (match) {
                int rank = __popcll(mask & ((1ull << lane) - 1ull));
                s_list[base + rank] = wpix + idx;
            }
        }
    }

    // ---- W_l column for this lane -> 64 VGPRs (sequential 16KB, L2-hot) ----
    float Wcol[64];
    const float* Wl = Wt + l*4096 + lane;
    #pragma unroll
    for (int c = 0; c < 64; ++c) Wcol[c] = Wl[c*64];
    float bias = bt[l*64 + lane];
    __syncthreads();
    const int m = s_n;

    float ssum = 0.f, sss = 0.f;
    for (int base0 = 0; base0 < m; base0 += 64) {
        int mm = min(64, m - base0);
        // stage matched xt rows (256B contiguous each) into LDS
        {
            int p = t >> 2, j = t & 3;
            if (p < mm) {
                const float4* r = (const float4*)xt + ((size_t)b*NPIX + s_list[base0+p])*16;
                #pragma unroll
                for (int k = 0; k < 4; ++k)
                    ((float4*)(s_x + p*64 + j*16))[k] = r[j*4 + k];
            }
        }
        __syncthreads();
        for (int i = wv; i < mm; i += 4) {
            const float4* xr = (const float4*)(s_x + i*64);
            float a0 = bias, a1 = 0.f, a2 = 0.f, a3 = 0.f;
            #pragma unroll
            for (int c4 = 0; c4 < 16; c4 += 4) {
                float4 q0 = xr[c4+0], q1 = xr[c4+1], q2 = xr[c4+2], q3 = xr[c4+3];
                a0 = fmaf(q0.x, Wcol[4*c4+ 0], a0); a0 = fmaf(q0.y, Wcol[4*c4+ 1], a0);
                a0 = fmaf(q0.z, Wcol[4*c4+ 2], a0); a0 = fmaf(q0.w, Wcol[4*c4+ 3], a0);
                a1 = fmaf(q1.x, Wcol[4*c4+ 4], a1); a1 = fmaf(q1.y, Wcol[4*c4+ 5], a1);
                a1 = fmaf(q1.z, Wcol[4*c4+ 6], a1); a1 = fmaf(q1.w, Wcol[4*c4+ 7], a1);
                a2 = fmaf(q2.x, Wcol[4*c4+ 8], a2); a2 = fmaf(q2.y, Wcol[4*c4+ 9], a2);
                a2 = fmaf(q2.z, Wcol[4*c4+10], a2); a2 = fmaf(q2.w, Wcol[4*c4+11], a2);
                a3 = fmaf(q3.x, Wcol[4*c4+12], a3); a3 = fmaf(q3.y, Wcol[4*c4+13], a3);
                a3 = fmaf(q3.z, Wcol[4*c4+14], a3); a3 = fmaf(q3.w, Wcol[4*c4+15], a3);
            }
            float acc = (a0 + a1) + (a2 + a3);
            yt[((size_t)b*NPIX + s_list[base0+i])*64 + lane] = acc;  // 256B coalesced
            ssum += acc; sss += acc*acc;
        }
        __syncthreads();   // protect s_x before next stage
    }

    s_red[wv][lane][0] = ssum;
    s_red[wv][lane][1] = sss;
    __syncthreads();
    if (wv == 0) {
        float S  = s_red[0][lane][0]+s_red[1][lane][0]+s_red[2][lane][0]+s_red[3][lane][0];
        float SS = s_red[0][lane][1]+s_red[1][lane][1]+s_red[2][lane][1]+s_red[3][lane][1];
        if (S != 0.f || SS != 0.f) {
            atomicAdd(&sums[(b*64+lane)*2+0], S);   // fire-and-forget (no return use)
            atomicAdd(&sums[(b*64+lane)*2+1], SS);
        }
    }
}

// ---- K3: transpose yt -> out with inline stats + instance-norm + leaky fused
__global__ __launch_bounds__(256) void norm_kernel(
    const float* __restrict__ yt, const float* __restrict__ sums,
    float* __restrict__ out)
{
    __shared__ float s_t[64*65];   // [o][p] stride 65
    __shared__ float s_mean[64], s_rstd[64];

    const int t  = threadIdx.x;
    const int bk = blockIdx.x;           // 512: b x ptile
    const int b  = bk >> 8;
    const int p0 = (bk & 255) << 6;

    if (t < 64) {
        float S  = sums[(b*64+t)*2+0];
        float SS = sums[(b*64+t)*2+1];
        const float invN = 1.0f/16384.0f;
        float mean = S * invN;
        float var  = SS * invN - mean*mean;
        s_mean[t] = mean;
        s_rstd[t] = rsqrtf(var + 1e-5f);
    }

    const float4* y4 = (const float4*)yt + ((size_t)b*NPIX + p0)*16;
    #pragma unroll
    for (int k = 0; k < 4; ++k) {
        int g = k*256 + t;
        int p = g >> 4, o4 = g & 15;
        float4 q = y4[p*16 + o4];
        int base = (o4*4)*65 + p;
        s_t[base]     = q.x;
        s_t[base+65]  = q.y;
        s_t[base+130] = q.z;
        s_t[base+195] = q.w;
    }
    __syncthreads();

    const int p = t & 63, og = (t >> 6) * 16;
    float* op = out + ((size_t)b*64 + og)*NPIX + p0 + p;
    #pragma unroll
    for (int kk = 0; kk < 16; ++kk) {
        int o = og + kk;
        float v = (s_t[o*65 + p] - s_mean[o]) * s_rstd[o];
        op[(size_t)kk*NPIX] = (v >= 0.f) ? v : 0.01f*v;
    }
}

extern "C" void kernel_launch(void* const* d_in, const int* in_sizes, int n_in,
                              void* d_out, int out_size, void* d_ws, size_t ws_size,
                              hipStream_t stream) {
    const float* x      = (const float*)d_in[0];
    const float* layout = (const float*)d_in[1];
    const float* pr     = (const float*)d_in[2];
    const float* cw     = (const float*)d_in[3];
    const float* cb     = (const float*)d_in[4];
    const float* Wt     = (const float*)d_in[5];
    const float* bt     = (const float*)d_in[6];
    const float* pl     = (const float*)d_in[7];
    float* out = (float*)d_out;

    char* ws = (char*)d_ws;
    size_t off = 0;
    float* xt     = (float*)(ws + off); off += (size_t)2*NPIX*64*4;   // 8 MB
    float* yt     = (float*)(ws + off); off += (size_t)2*NPIX*64*4;   // 8 MB
    int*   argbuf = (int*)  (ws + off); off += (size_t)2*NPIX*4;      // 128 KB
    float* sums   = (float*)(ws + off); off += 256*4;                 // 128 (b,o) x {S,SS}

    prep_kernel <<<NB1, 256, 0, stream>>>(x, layout, pr, cw, cb, pl, xt, argbuf, sums);
    gemm_kernel <<<NG,  256, 0, stream>>>(Wt, bt, xt, argbuf, yt, sums);
    norm_kernel <<<NB1, 256, 0, stream>>>(yt, sums, out);
}